// Round 4
// baseline (72.982 us; speedup 1.0000x reference)
//
#include <hip/hip_runtime.h>
#include <hip/hip_bf16.h>

// TTT-M1 decode step (CS=1), B=128 H=32 HF=64.  f32 in / f32 out.
//   z1[d]      = sum_f xb[f]*W[f][d] - xa[d]
//   g_new[f,d] = g[f,d] + xb[f]*z1[d]
//   w_new[f,d] = W[f,d] - coeff*g_new[f,d]
//   out[d]     = sum_f xc[f]*w_new[f,d]
//
// One WAVE per (b,h): no LDS, no barriers. Lane l: fg=l>>4 owns rows
// 16fg..16fg+15; cols d0=4*(l&15)..d0+3 (float4 slices). z1/Out reductions
// are 2x __shfl_xor (^16,^32). W rows live in 64 VGPRs across both passes.
// Output W/G streams use nontemporal stores (ext_vector_type for the
// builtin) so the 137MB input set stays L3-resident across graph replays.

namespace {

constexpr int HFD = 64;

typedef float f32x4 __attribute__((ext_vector_type(4)));

__global__ __launch_bounds__(256, 4) void ttt_m1_decode_wave(
    const float* __restrict__ W1i,
    const float* __restrict__ W1g,
    const float* __restrict__ XA,
    const float* __restrict__ XB,
    const float* __restrict__ XC,
    const float* __restrict__ coeff,
    float* __restrict__ oOut,   // [BH*64]
    float* __restrict__ oW1,    // [BH*4096]
    float* __restrict__ oG)     // [BH*4096]
{
    const int tid  = threadIdx.x;
    const int wave = tid >> 6;
    const int lane = tid & 63;
    const int bh   = blockIdx.x * 4 + wave;
    const int fg   = lane >> 4;          // row group: rows 16fg..16fg+15
    const int d0   = (lane & 15) << 2;   // column slice d0..d0+3

    const size_t mbase = (size_t)bh * (HFD * HFD);
    const float* Wi = W1i + mbase;
    const float* Wg = W1g + mbase;
    const float* xa = XA + bh * HFD;
    const float* xb = XB + bh * HFD;
    const float* xc = XC + bh * HFD;
    const float cf  = coeff[bh];

    // ---- pass A: W rows -> regs, z partials over our 16 rows ----
    f32x4 w[16];
    f32x4 z = (f32x4)0.f;
#pragma unroll
    for (int j = 0; j < 16; ++j) {
        const int f = fg * 16 + j;
        w[j] = *reinterpret_cast<const f32x4*>(Wi + f * HFD + d0);
        const float xbf = xb[f];
        z += xbf * w[j];
    }
    // reduce z over the 4 row groups (all lanes end with the full sum)
#pragma unroll
    for (int k = 0; k < 4; ++k) {
        z[k] += __shfl_xor(z[k], 16, 64);
        z[k] += __shfl_xor(z[k], 32, 64);
    }
    z -= *reinterpret_cast<const f32x4*>(xa + d0);

    // ---- pass B: grad update, weight update, out partials, stores ----
    f32x4 o = (f32x4)0.f;
#pragma unroll
    for (int j = 0; j < 16; ++j) {
        const int f = fg * 16 + j;
        f32x4 g = *reinterpret_cast<const f32x4*>(Wg + f * HFD + d0);
        const float xbf = xb[f];
        const float xcf = xc[f];
        f32x4 gn = g + xbf * z;
        f32x4 wn = w[j] - cf * gn;
        o += xcf * wn;
        const size_t off = mbase + (size_t)f * HFD + d0;
        __builtin_nontemporal_store(gn, reinterpret_cast<f32x4*>(oG  + off));
        __builtin_nontemporal_store(wn, reinterpret_cast<f32x4*>(oW1 + off));
    }
    // reduce out partials over the 4 row groups
#pragma unroll
    for (int k = 0; k < 4; ++k) {
        o[k] += __shfl_xor(o[k], 16, 64);
        o[k] += __shfl_xor(o[k], 32, 64);
    }
    if (fg == 0)
        *reinterpret_cast<f32x4*>(oOut + bh * HFD + d0) = o;
}

} // namespace

extern "C" void kernel_launch(void* const* d_in, const int* in_sizes, int n_in,
                              void* d_out, int out_size, void* d_ws, size_t ws_size,
                              hipStream_t stream) {
    const float* W1i = (const float*)d_in[0];
    const float* W1g = (const float*)d_in[1];
    const float* XA  = (const float*)d_in[2];
    const float* XB  = (const float*)d_in[3];
    const float* XC  = (const float*)d_in[4];
    const float* cf  = (const float*)d_in[5];

    const int BH = in_sizes[0] / (64 * 64);  // 128*32 = 4096

    float* out  = (float*)d_out;
    float* oOut = out;                        // Out:        BH*64
    float* oW1  = out + (size_t)BH * 64;      // W1_init_new BH*4096
    float* oG   = oW1 + (size_t)BH * 4096;    // W1_grad_new BH*4096

    // 4 waves per block, one (b,h) per wave
    ttt_m1_decode_wave<<<BH / 4, 256, 0, stream>>>(W1i, W1g, XA, XB, XC, cf,
                                                   oOut, oW1, oG);
}

// Round 5
// 54.579 us; speedup vs baseline: 1.3372x; 1.3372x over previous
//
#include <hip/hip_runtime.h>
#include <hip/hip_bf16.h>

// TTT-M1 decode step (CS=1), B=128 H=32 HF=64.  f32 in / f32 out.
//   z1[d]      = sum_f xb[f]*W[f][d] - xa[d]
//   g_new[f,d] = g[f,d] + xb[f]*z1[d]
//   w_new[f,d] = W[f,d] - coeff*g_new[f,d]
//   out[d]     = sum_f xc[f]*w_new[f,d]
//
// One 256-thread block per (b,h); each of the 4 waves independently owns a
// 16-column stripe (wc*16..wc*16+15) of the 64x64 matrices. No LDS, no
// barriers, no cross-wave traffic. Lane: rg=lane>>2 (row group), cq=lane&3
// (f32x4 col slice); lane owns rows {rg+16j, j=0..3} x cols d0..d0+3. W rows
// live in 4xf32x4 regs across both passes. z1/Out reductions are 4x
// __shfl_xor (^4,^8,^16,^32). Regular (cacheable) stores so L3 write-back
// absorbs the output stream between graph replays (nt stores regressed:
// WRITE_SIZE 132->180MB, round 4).

namespace {

constexpr int HFD = 64;

typedef float f32x4 __attribute__((ext_vector_type(4)));

__global__ __launch_bounds__(256, 8) void ttt_m1_decode_stripe(
    const float* __restrict__ W1i,
    const float* __restrict__ W1g,
    const float* __restrict__ XA,
    const float* __restrict__ XB,
    const float* __restrict__ XC,
    const float* __restrict__ coeff,
    float* __restrict__ oOut,   // [BH*64]
    float* __restrict__ oW1,    // [BH*4096]
    float* __restrict__ oG)     // [BH*4096]
{
    const int tid  = threadIdx.x;
    const int wc   = tid >> 6;            // wave -> column stripe (0..3)
    const int lane = tid & 63;
    const int rg   = lane >> 2;           // row group 0..15
    const int cq   = lane & 3;            // col slice within stripe
    const int d0   = wc * 16 + cq * 4;    // first of 4 owned columns
    const int bh   = blockIdx.x;

    const size_t mbase = (size_t)bh * (HFD * HFD);
    const float* Wi = W1i + mbase;
    const float* Wg = W1g + mbase;
    const float* xa = XA + bh * HFD;
    const float* xb = XB + bh * HFD;
    const float* xc = XC + bh * HFD;
    const float cf  = coeff[bh];

    // ---- pass A: W rows -> regs, z partials over our 4 rows ----
    f32x4 w[4];
    f32x4 z = (f32x4)0.f;
#pragma unroll
    for (int j = 0; j < 4; ++j) {
        const int f = rg + j * 16;
        w[j] = *reinterpret_cast<const f32x4*>(Wi + f * HFD + d0);
        z += xb[f] * w[j];
    }
    // reduce z over the 16 row groups (rg lives in lane bits 2..5)
#pragma unroll
    for (int k = 0; k < 4; ++k) {
        z[k] += __shfl_xor(z[k], 4, 64);
        z[k] += __shfl_xor(z[k], 8, 64);
        z[k] += __shfl_xor(z[k], 16, 64);
        z[k] += __shfl_xor(z[k], 32, 64);
    }
    z -= *reinterpret_cast<const f32x4*>(xa + d0);

    // ---- pass B: grad update, weight update, out partials, stores ----
    f32x4 o = (f32x4)0.f;
#pragma unroll
    for (int j = 0; j < 4; ++j) {
        const int f = rg + j * 16;
        f32x4 g = *reinterpret_cast<const f32x4*>(Wg + f * HFD + d0);
        f32x4 gn = g + xb[f] * z;
        f32x4 wn = w[j] - cf * gn;
        o += xc[f] * wn;
        const size_t off = mbase + (size_t)f * HFD + d0;
        *reinterpret_cast<f32x4*>(oG  + off) = gn;
        *reinterpret_cast<f32x4*>(oW1 + off) = wn;
    }
    // reduce out partials over the 16 row groups
#pragma unroll
    for (int k = 0; k < 4; ++k) {
        o[k] += __shfl_xor(o[k], 4, 64);
        o[k] += __shfl_xor(o[k], 8, 64);
        o[k] += __shfl_xor(o[k], 16, 64);
        o[k] += __shfl_xor(o[k], 32, 64);
    }
    if (rg == 0)
        *reinterpret_cast<f32x4*>(oOut + bh * HFD + d0) = o;
}

} // namespace

extern "C" void kernel_launch(void* const* d_in, const int* in_sizes, int n_in,
                              void* d_out, int out_size, void* d_ws, size_t ws_size,
                              hipStream_t stream) {
    const float* W1i = (const float*)d_in[0];
    const float* W1g = (const float*)d_in[1];
    const float* XA  = (const float*)d_in[2];
    const float* XB  = (const float*)d_in[3];
    const float* XC  = (const float*)d_in[4];
    const float* cf  = (const float*)d_in[5];

    const int BH = in_sizes[0] / (64 * 64);  // 128*32 = 4096

    float* out  = (float*)d_out;
    float* oOut = out;                        // Out:        BH*64
    float* oW1  = out + (size_t)BH * 64;      // W1_init_new BH*4096
    float* oG   = oW1 + (size_t)BH * 4096;    // W1_grad_new BH*4096

    ttt_m1_decode_stripe<<<BH, 256, 0, stream>>>(W1i, W1g, XA, XB, XC, cf,
                                                 oOut, oW1, oG);
}

// Round 6
// 46.742 us; speedup vs baseline: 1.5614x; 1.1677x over previous
//
#include <hip/hip_runtime.h>
#include <hip/hip_bf16.h>

// TTT-M1 decode step (CS=1), B=128 H=32 HF=64.  f32 in / f32 out.
//   z1[d]      = sum_f xb[f]*W[f][d] - xa[d]
//   g_new[f,d] = g[f,d] + xb[f]*z1[d]
//   w_new[f,d] = W[f,d] - coeff*g_new[f,d]
//   out[d]     = sum_f xc[f]*w_new[f,d]
//
// Round-2 structure (one 256-thread block per (b,h), thread (c=tid&15,
// r=tid>>4) owns a 4x4 sub-tile -> 1KB-contiguous wave loads/stores, LDS
// reductions, 2 barriers; proven 46.5us) plus:
//  * NONTEMPORAL loads for W1i/W1g: these lines have zero intra-replay
//    reuse (each consumed once by one wave-instruction). Streaming them
//    leaves the 256MB L3 to hold the 135MB output set across graph
//    replays (outputs are rewritten every replay -> writeback absorbed).
//  * W1g tile prefetched into registers BEFORE the z-barrier (compiler
//    cannot hoist loads across __syncthreads), so pass B never stalls.

namespace {

constexpr int HFD = 64;

typedef float f32x4 __attribute__((ext_vector_type(4)));

__global__ __launch_bounds__(256, 4) void ttt_m1_decode(
    const float* __restrict__ W1i,
    const float* __restrict__ W1g,
    const float* __restrict__ XA,
    const float* __restrict__ XB,
    const float* __restrict__ XC,
    const float* __restrict__ coeff,
    float* __restrict__ oOut,   // [BH*64]
    float* __restrict__ oW1,    // [BH*4096]
    float* __restrict__ oG)     // [BH*4096]
{
    const int bh  = blockIdx.x;
    const int tid = threadIdx.x;
    const int c   = tid & 15;   // column group (4 cols)
    const int r   = tid >> 4;   // row group   (4 rows), 0..15
    const int d0  = c << 2;
    const int f0  = r << 2;

    const size_t mbase = (size_t)bh * (HFD * HFD);
    const float* Wi = W1i + mbase;
    const float* Wg = W1g + mbase;
    const float* xa = XA + bh * HFD;
    const float* xb = XB + bh * HFD;
    const float* xc = XC + bh * HFD;
    const float cf  = coeff[bh];

    __shared__ float redZ[16][HFD];
    __shared__ float redO[16][HFD];

    // --- load 4x4 tiles of W1_init AND W1_grad (prefetch) as f32x4 rows ---
    f32x4 wi[4], wg[4];
#pragma unroll
    for (int j = 0; j < 4; ++j) {
        wi[j] = __builtin_nontemporal_load(
            reinterpret_cast<const f32x4*>(Wi + (f0 + j) * HFD + d0));
        wg[j] = __builtin_nontemporal_load(
            reinterpret_cast<const f32x4*>(Wg + (f0 + j) * HFD + d0));
    }
    float xbv[4], xcv[4];
#pragma unroll
    for (int j = 0; j < 4; ++j) { xbv[j] = xb[f0 + j]; xcv[j] = xc[f0 + j]; }
    const f32x4 xav = *reinterpret_cast<const f32x4*>(xa + d0);

    // --- partial z over our 4 rows, for our 4 columns ---
    f32x4 zp = xbv[0]*wi[0] + xbv[1]*wi[1] + xbv[2]*wi[2] + xbv[3]*wi[3];
    *reinterpret_cast<f32x4*>(&redZ[r][d0]) = zp;
    __syncthreads();

    // --- full z1 for our 4 columns (sum of 16 row-group partials) ---
    f32x4 z = (f32x4)0.f;
#pragma unroll
    for (int rp = 0; rp < 16; ++rp)
        z += *reinterpret_cast<const f32x4*>(&redZ[rp][d0]);
    z -= xav;

    // --- update grad & weights (wg already in regs), store, out partial ---
    f32x4 o = (f32x4)0.f;
#pragma unroll
    for (int j = 0; j < 4; ++j) {
        f32x4 gn = wg[j] + xbv[j] * z;
        f32x4 wn = wi[j] - cf * gn;
        o += xcv[j] * wn;
        const size_t off = mbase + (size_t)(f0 + j) * HFD + d0;
        *reinterpret_cast<f32x4*>(oG  + off) = gn;   // regular, L3-cacheable
        *reinterpret_cast<f32x4*>(oW1 + off) = wn;
    }

    *reinterpret_cast<f32x4*>(&redO[r][d0]) = o;
    __syncthreads();

    // --- reduce out partials; lanes 0..63 write Out[d] ---
    if (tid < HFD) {
        float s = 0.f;
#pragma unroll
        for (int rp = 0; rp < 16; ++rp) s += redO[rp][tid];
        oOut[bh * HFD + tid] = s;
    }
}

} // namespace

extern "C" void kernel_launch(void* const* d_in, const int* in_sizes, int n_in,
                              void* d_out, int out_size, void* d_ws, size_t ws_size,
                              hipStream_t stream) {
    const float* W1i = (const float*)d_in[0];
    const float* W1g = (const float*)d_in[1];
    const float* XA  = (const float*)d_in[2];
    const float* XB  = (const float*)d_in[3];
    const float* XC  = (const float*)d_in[4];
    const float* cf  = (const float*)d_in[5];

    const int BH = in_sizes[0] / (64 * 64);  // 128*32 = 4096

    float* out  = (float*)d_out;
    float* oOut = out;                        // Out:        BH*64
    float* oW1  = out + (size_t)BH * 64;      // W1_init_new BH*4096
    float* oG   = oW1 + (size_t)BH * 4096;    // W1_grad_new BH*4096

    ttt_m1_decode<<<BH, 256, 0, stream>>>(W1i, W1g, XA, XB, XC, cf,
                                          oOut, oW1, oG);
}